// Round 3
// baseline (114.762 us; speedup 1.0000x reference)
//
#include <hip/hip_runtime.h>
#include <hip/hip_bf16.h>

typedef __attribute__((ext_vector_type(4))) float f32x4;
typedef __attribute__((ext_vector_type(8))) short bf16x8;
typedef __attribute__((ext_vector_type(4))) unsigned short u16x4;

#define DEVI __device__ __forceinline__

constexpr int B_ = 4, S_ = 1024, D_ = 512, H_ = 8, HD_ = 64;
constexpr float CSH = 11.0903548f;  // fixed softmax shift (folded into bias table)

DEVI unsigned short f2b(float f) {
  union { float f; unsigned u; } v; v.f = f;
  unsigned r = v.u + 0x7fffu + ((v.u >> 16) & 1u);
  return (unsigned short)(r >> 16);
}

// ---------------- prep: weight transpose+bf16 (z=0..3) and bias MLP table (z=4) ----------------
__global__ __launch_bounds__(256) void k_prep(const float* Wa, const float* Wb,
                                              const float* Wc, const float* Wd,
                                              unsigned short* T0, unsigned short* T1,
                                              unsigned short* T2, unsigned short* T3,
                                              const float* mW1, const float* mb1,
                                              const float* mW2, const float* mb2,
                                              float* table) {
  if (blockIdx.z == 4) {
    if (blockIdx.y != 0) return;
    int idx = blockIdx.x * 256 + threadIdx.x;
    if (idx >= 63 * 63) return;
    int dy = idx / 63 - 31, dx = idx % 63 - 31;
    float r0 = copysignf(log1pf(fabsf((float)dy)), (float)dy);
    float r1 = copysignf(log1pf(fabsf((float)dx)), (float)dx);
    float acc[8];
#pragma unroll
    for (int h = 0; h < 8; ++h) acc[h] = mb2[h];
    for (int j = 0; j < 128; ++j) {
      float hv = fmaxf(r0 * mW1[j] + r1 * mW1[128 + j] + mb1[j], 0.f);
#pragma unroll
      for (int h = 0; h < 8; ++h) acc[h] += hv * mW2[j * 8 + h];
    }
#pragma unroll
    for (int h = 0; h < 8; ++h) table[h * 3969 + idx] = acc[h] - CSH;  // shift folded in
    return;
  }
  const float* W = blockIdx.z == 0 ? Wa : blockIdx.z == 1 ? Wb : blockIdx.z == 2 ? Wc : Wd;
  unsigned short* T = blockIdx.z == 0 ? T0 : blockIdx.z == 1 ? T1 : blockIdx.z == 2 ? T2 : T3;
  __shared__ float tile[32][33];
  int tx = threadIdx.x & 31, ty = threadIdx.x >> 5;
  int n0 = blockIdx.x * 32, k0 = blockIdx.y * 32;
#pragma unroll
  for (int r = 0; r < 4; ++r) tile[ty + r * 8][tx] = W[(size_t)(k0 + ty + r * 8) * D_ + n0 + tx];
  __syncthreads();
#pragma unroll
  for (int r = 0; r < 4; ++r) T[(size_t)(n0 + ty + r * 8) * D_ + k0 + tx] = f2b(tile[tx][ty + r * 8]);
}

// ---------------- merged QKV GEMM; V written pre-transposed [bh][hd][s] ----------------
__global__ __launch_bounds__(256) void k_gemm_qkv(const float* Aq, const float* Ak, const float* Av,
                                                  const unsigned short* Tq, const unsigned short* Tk,
                                                  const unsigned short* Tv,
                                                  const float* bqv, const float* bkv, const float* bvv,
                                                  unsigned short* Oq, unsigned short* Ok,
                                                  unsigned short* OvT) {
  const float* A = blockIdx.z == 0 ? Aq : blockIdx.z == 1 ? Ak : Av;
  const unsigned short* BT = blockIdx.z == 0 ? Tq : blockIdx.z == 1 ? Tk : Tv;
  const float* bias = blockIdx.z == 0 ? bqv : blockIdx.z == 1 ? bkv : bvv;

  __shared__ unsigned short As[128][40];
  __shared__ unsigned short Bs[128][40];
  const int tid = threadIdx.x;
  const int lane = tid & 63, wave = tid >> 6;
  const int lr = lane & 15, lg = lane >> 4;
  const int wm = (wave >> 1) * 64, wn = (wave & 1) * 64;
  const int m0 = blockIdx.x * 128, n0 = blockIdx.y * 128;

  f32x4 acc[4][4];
#pragma unroll
  for (int i = 0; i < 4; ++i)
#pragma unroll
    for (int j = 0; j < 4; ++j) acc[i][j] = (f32x4){0.f, 0.f, 0.f, 0.f};

  for (int k0 = 0; k0 < 512; k0 += 32) {
#pragma unroll
    for (int i = 0; i < 4; ++i) {
      int idx = tid + i * 256;
      int r = idx >> 3, c4 = (idx & 7) * 4;
      float4 fv = *(const float4*)(A + (size_t)(m0 + r) * 512 + k0 + c4);
      u16x4 wv;
      wv[0] = f2b(fv.x); wv[1] = f2b(fv.y); wv[2] = f2b(fv.z); wv[3] = f2b(fv.w);
      *(u16x4*)&As[r][c4] = wv;
      *(u16x4*)&Bs[r][c4] = *(const u16x4*)(BT + (size_t)(n0 + r) * 512 + k0 + c4);
    }
    __syncthreads();
    bf16x8 af[4], bg[4];
#pragma unroll
    for (int i = 0; i < 4; ++i) af[i] = *(const bf16x8*)&As[wm + i * 16 + lr][lg * 8];
#pragma unroll
    for (int j = 0; j < 4; ++j) bg[j] = *(const bf16x8*)&Bs[wn + j * 16 + lr][lg * 8];
#pragma unroll
    for (int i = 0; i < 4; ++i)
#pragma unroll
      for (int j = 0; j < 4; ++j)
        acc[i][j] = __builtin_amdgcn_mfma_f32_16x16x32_bf16(af[i], bg[j], acc[i][j], 0, 0, 0);
    __syncthreads();
  }

#pragma unroll
  for (int i = 0; i < 4; ++i)
#pragma unroll
    for (int j = 0; j < 4; ++j) {
      int mbase = m0 + wm + i * 16 + lg * 4;
      int n = n0 + wn + j * 16 + lr;
      float bvl = bias[n];
      int h = n >> 6, hd = n & 63;
      int bseg = mbase >> 10, s0 = mbase & 1023;
      if (blockIdx.z == 2) {
        // V: write transposed [bh][hd][s], 4 consecutive s per lane -> u16x4
        u16x4 pk;
#pragma unroll
        for (int r = 0; r < 4; ++r) pk[r] = f2b(acc[i][j][r] + bvl);
        *(u16x4*)(OvT + (((size_t)(bseg * H_ + h) * 64 + hd) * 1024 + s0)) = pk;
      } else {
        unsigned short* outp = blockIdx.z == 0 ? Oq : Ok;
#pragma unroll
        for (int r = 0; r < 4; ++r) {
          float v = acc[i][j][r] + bvl;
          outp[(((size_t)bseg * H_ + h) * S_ + s0 + r) * HD_ + hd] = f2b(v);
        }
      }
    }
}

// ---------------- output projection GEMM: bf16 A @ W^T + bias -> fp32 ----------------
__global__ __launch_bounds__(256) void k_gemm_out(const unsigned short* A, const unsigned short* BT,
                                                  const float* bias, float* outp) {
  __shared__ unsigned short As[128][40];
  __shared__ unsigned short Bs[128][40];
  const int tid = threadIdx.x;
  const int lane = tid & 63, wave = tid >> 6;
  const int lr = lane & 15, lg = lane >> 4;
  const int wm = (wave >> 1) * 64, wn = (wave & 1) * 64;
  const int m0 = blockIdx.x * 128, n0 = blockIdx.y * 128;

  f32x4 acc[4][4];
#pragma unroll
  for (int i = 0; i < 4; ++i)
#pragma unroll
    for (int j = 0; j < 4; ++j) acc[i][j] = (f32x4){0.f, 0.f, 0.f, 0.f};

  for (int k0 = 0; k0 < 512; k0 += 32) {
#pragma unroll
    for (int i = 0; i < 4; ++i) {
      int idx = tid + i * 256;
      int r = idx >> 3, c4 = (idx & 7) * 4;
      *(u16x4*)&As[r][c4] = *(const u16x4*)(A + (size_t)(m0 + r) * 512 + k0 + c4);
      *(u16x4*)&Bs[r][c4] = *(const u16x4*)(BT + (size_t)(n0 + r) * 512 + k0 + c4);
    }
    __syncthreads();
    bf16x8 af[4], bg[4];
#pragma unroll
    for (int i = 0; i < 4; ++i) af[i] = *(const bf16x8*)&As[wm + i * 16 + lr][lg * 8];
#pragma unroll
    for (int j = 0; j < 4; ++j) bg[j] = *(const bf16x8*)&Bs[wn + j * 16 + lr][lg * 8];
#pragma unroll
    for (int i = 0; i < 4; ++i)
#pragma unroll
      for (int j = 0; j < 4; ++j)
        acc[i][j] = __builtin_amdgcn_mfma_f32_16x16x32_bf16(af[i], bg[j], acc[i][j], 0, 0, 0);
    __syncthreads();
  }

#pragma unroll
  for (int i = 0; i < 4; ++i)
#pragma unroll
    for (int j = 0; j < 4; ++j) {
      int mbase = m0 + wm + i * 16 + lg * 4;
      int n = n0 + wn + j * 16 + lr;
      float bvl = bias[n];
#pragma unroll
      for (int r = 0; r < 4; ++r)
        outp[(size_t)(mbase + r) * 512 + n] = acc[i][j][r] + bvl;
    }
}

// ---------------- fused two-pass attention: 512 thr / 8 waves / 128 q-rows per block ----------------
__global__ __launch_bounds__(512) void k_attn(const unsigned short* Qb, const unsigned short* Kb,
                                              const unsigned short* VT, const float* tbl,
                                              const int* mask, float* out_attn,
                                              unsigned short* Xp) {
  const int tid = threadIdx.x;
  const int lane = tid & 63, w = tid >> 6;
  const int lr = lane & 15, lg = lane >> 4;
  const int bh = blockIdx.y, b = bh >> 3, h = bh & 7;
  const int q0 = blockIdx.x * 128;

  __shared__ unsigned short Ks[2][64][64];   // K tiles, double-buffered, XOR-swizzled 16B chunks
  __shared__ unsigned short Vt[2][64][64];   // V^T tiles, double-buffered, same swizzle
  __shared__ unsigned short Pl[8][16][64];   // per-wave P tile
  __shared__ float biasT[3969];
  __shared__ float mbig[1024];
  __shared__ int tbad[16];

  const unsigned short* Qh = Qb + (size_t)bh * (S_ * HD_);
  const unsigned short* Kh = Kb + (size_t)bh * (S_ * HD_);
  const unsigned short* Vth = VT + (size_t)bh * (HD_ * S_);

  const int srow = tid >> 3, sc = tid & 7;       // staging task: one 16B chunk per thread
  const int swz = (sc ^ (srow & 7)) * 8;

  if (tid < 16) tbad[tid] = 0;
  __syncthreads();
  for (int i = tid; i < 3969; i += 512) biasT[i] = tbl[h * 3969 + i];
  {
    int i = tid << 1;
    int m0v = mask[b * S_ + i], m1v = mask[b * S_ + i + 1];
    mbig[i] = m0v ? 3.0e38f : -1.0e9f;
    mbig[i + 1] = m1v ? 3.0e38f : -1.0e9f;
    if (!m0v || !m1v) tbad[i >> 6] = 1;
  }
  *(bf16x8*)&Ks[0][srow][swz] = *(const bf16x8*)(Kh + (size_t)srow * 64 + sc * 8);

  const int qrow = q0 + w * 16 + lr;
  const bf16x8 bq0 = *(const bf16x8*)(Qh + (size_t)qrow * 64 + lg * 8);
  const bf16x8 bq1 = *(const bf16x8*)(Qh + (size_t)qrow * 64 + 32 + lg * 8);
  const int qterm = (qrow >> 5) * 63 + (qrow & 31) + 1984;

  float ls = 0.f;
  __syncthreads();

  // ---- PASS 1: row sums (fixed-shift, no max tracking) ----
  for (int kt = 0; kt < 16; ++kt) {
    const int cur = kt & 1;
    bf16x8 nk;
    if (kt < 15) nk = *(const bf16x8*)(Kh + (size_t)((kt + 1) * 64 + srow) * 64 + sc * 8);
    const int bidx = qterm - 126 * kt;
    const bool bad = tbad[kt] != 0;
#pragma unroll
    for (int fn = 0; fn < 4; ++fn) {
      const unsigned short* krow = &Ks[cur][fn * 16 + lr][0];
      bf16x8 a0 = *(const bf16x8*)(krow + (lg ^ (lr & 7)) * 8);
      bf16x8 a1 = *(const bf16x8*)(krow + ((4 + lg) ^ (lr & 7)) * 8);
      f32x4 s = (f32x4){0.f, 0.f, 0.f, 0.f};
      s = __builtin_amdgcn_mfma_f32_16x16x32_bf16(a0, bq0, s, 0, 0, 0);
      s = __builtin_amdgcn_mfma_f32_16x16x32_bf16(a1, bq1, s, 0, 0, 0);
      const int kob = fn * 16 + lg * 4;
      const int ib = bidx - kob - (fn >= 2 ? 31 : 0);
#pragma unroll
      for (int r = 0; r < 4; ++r) {
        float arg = fmaf(s[r], 0.125f, biasT[ib - r]);
        if (bad) arg = fminf(arg, mbig[kt * 64 + kob + r]);
        ls += __expf(arg);
      }
    }
    if (kt < 15) *(bf16x8*)&Ks[cur ^ 1][srow][swz] = nk;
    __syncthreads();
  }
  ls += __shfl_xor(ls, 16, 64);
  ls += __shfl_xor(ls, 32, 64);
  const float inv = 1.f / ls;

  // ---- PASS 2: recompute, write attention (float4), accumulate PV ----
  f32x4 of[4];
#pragma unroll
  for (int i = 0; i < 4; ++i) of[i] = (f32x4){0.f, 0.f, 0.f, 0.f};
  float* oa = out_attn + (size_t)bh * (S_ * S_) + (size_t)qrow * S_;

  *(bf16x8*)&Ks[0][srow][swz] = *(const bf16x8*)(Kh + (size_t)srow * 64 + sc * 8);
  *(bf16x8*)&Vt[0][srow][swz] = *(const bf16x8*)(Vth + (size_t)srow * S_ + sc * 8);
  __syncthreads();

  for (int kt = 0; kt < 16; ++kt) {
    const int cur = kt & 1;
    bf16x8 nk, nv;
    if (kt < 15) {
      nk = *(const bf16x8*)(Kh + (size_t)((kt + 1) * 64 + srow) * 64 + sc * 8);
      nv = *(const bf16x8*)(Vth + (size_t)srow * S_ + (kt + 1) * 64 + sc * 8);
    }
    const int bidx = qterm - 126 * kt;
    const bool bad = tbad[kt] != 0;
#pragma unroll
    for (int fn = 0; fn < 4; ++fn) {
      const unsigned short* krow = &Ks[cur][fn * 16 + lr][0];
      bf16x8 a0 = *(const bf16x8*)(krow + (lg ^ (lr & 7)) * 8);
      bf16x8 a1 = *(const bf16x8*)(krow + ((4 + lg) ^ (lr & 7)) * 8);
      f32x4 s = (f32x4){0.f, 0.f, 0.f, 0.f};
      s = __builtin_amdgcn_mfma_f32_16x16x32_bf16(a0, bq0, s, 0, 0, 0);
      s = __builtin_amdgcn_mfma_f32_16x16x32_bf16(a1, bq1, s, 0, 0, 0);
      const int kob = fn * 16 + lg * 4;
      const int ib = bidx - kob - (fn >= 2 ? 31 : 0);
      f32x4 pr;
      u16x4 pb;
#pragma unroll
      for (int r = 0; r < 4; ++r) {
        float arg = fmaf(s[r], 0.125f, biasT[ib - r]);
        if (bad) arg = fminf(arg, mbig[kt * 64 + kob + r]);
        float p = __expf(arg) * inv;
        pr[r] = p;
        pb[r] = f2b(p);
      }
      *(f32x4*)(oa + kt * 64 + kob) = pr;
      *(u16x4*)((char*)&Pl[w][lr][0] + ((fn * 2 + (lg >> 1)) ^ (lr & 7)) * 16 + (lg & 1) * 8) = pb;
    }
    // PV: O[q][d] += P[q][k] V[k][d]
#pragma unroll
    for (int c = 0; c < 2; ++c) {
      bf16x8 pa = *(const bf16x8*)((const char*)&Pl[w][lr][0] + ((c * 4 + lg) ^ (lr & 7)) * 16);
#pragma unroll
      for (int fn2 = 0; fn2 < 4; ++fn2) {
        const unsigned short* vrow = &Vt[cur][fn2 * 16 + lr][0];
        bf16x8 bv = *(const bf16x8*)((const char*)vrow + ((c * 4 + lg) ^ (lr & 7)) * 16);
        of[fn2] = __builtin_amdgcn_mfma_f32_16x16x32_bf16(pa, bv, of[fn2], 0, 0, 0);
      }
    }
    if (kt < 15) {
      *(bf16x8*)&Ks[cur ^ 1][srow][swz] = nk;
      *(bf16x8*)&Vt[cur ^ 1][srow][swz] = nv;
    }
    __syncthreads();
  }

  // epilogue: x pre-projection, bf16 [B,S,D]
#pragma unroll
  for (int fn2 = 0; fn2 < 4; ++fn2)
#pragma unroll
    for (int r = 0; r < 4; ++r) {
      int q = q0 + w * 16 + lg * 4 + r;
      Xp[((size_t)b * S_ + q) * D_ + h * 64 + fn2 * 16 + lr] = f2b(of[fn2][r]);
    }
}

// ---------------- host launch ----------------
extern "C" void kernel_launch(void* const* d_in, const int* in_sizes, int n_in,
                              void* d_out, int out_size, void* d_ws, size_t ws_size,
                              hipStream_t stream) {
  const float* query = (const float*)d_in[0];
  const float* key   = (const float*)d_in[1];
  const float* value = (const float*)d_in[2];
  const int*   maskp = (const int*)d_in[3];
  const float* Wq = (const float*)d_in[4];
  const float* bq = (const float*)d_in[5];
  const float* Wk = (const float*)d_in[6];
  const float* bk = (const float*)d_in[7];
  const float* Wv = (const float*)d_in[8];
  const float* bv = (const float*)d_in[9];
  const float* Wo = (const float*)d_in[10];
  const float* bo = (const float*)d_in[11];
  const float* W1 = (const float*)d_in[12];
  const float* b1 = (const float*)d_in[13];
  const float* W2 = (const float*)d_in[14];
  const float* b2 = (const float*)d_in[15];

  char* ws = (char*)d_ws;
  const size_t MB4 = (size_t)4 * 1024 * 1024;
  unsigned short* Qb  = (unsigned short*)(ws);
  unsigned short* Kb  = (unsigned short*)(ws + MB4);
  unsigned short* VT  = (unsigned short*)(ws + 2 * MB4);
  unsigned short* Xp  = (unsigned short*)(ws + 3 * MB4);
  unsigned short* WqT = (unsigned short*)(ws + 4 * MB4);
  unsigned short* WkT = (unsigned short*)(ws + 4 * MB4 + 524288);
  unsigned short* WvT = (unsigned short*)(ws + 4 * MB4 + 2 * 524288);
  unsigned short* WoT = (unsigned short*)(ws + 4 * MB4 + 3 * 524288);
  float* table        = (float*)(ws + 4 * MB4 + 4 * 524288);

  float* out_x = (float*)d_out;
  float* out_attn = out_x + (size_t)B_ * S_ * D_;

  k_prep<<<dim3(16, 16, 5), 256, 0, stream>>>(Wq, Wk, Wv, Wo, WqT, WkT, WvT, WoT,
                                              W1, b1, W2, b2, table);
  k_gemm_qkv<<<dim3(32, 4, 3), 256, 0, stream>>>(query, key, value, WqT, WkT, WvT,
                                                 bq, bk, bv, Qb, Kb, VT);
  k_attn<<<dim3(8, 32), 512, 0, stream>>>(Qb, Kb, VT, table, maskp, out_attn, Xp);
  k_gemm_out<<<dim3(32, 4), 256, 0, stream>>>(Xp, WoT, bo, out_x);
}

// Round 4
// 100.746 us; speedup vs baseline: 1.1391x; 1.1391x over previous
//
#include <hip/hip_runtime.h>
#include <hip/hip_bf16.h>

typedef __attribute__((ext_vector_type(4))) float f32x4;
typedef __attribute__((ext_vector_type(8))) short bf16x8;
typedef __attribute__((ext_vector_type(4))) unsigned short u16x4;

#define DEVI __device__ __forceinline__

constexpr int B_ = 4, S_ = 1024, D_ = 512, H_ = 8, HD_ = 64;
constexpr float CSH = 11.0903548f;  // fixed softmax shift (folded into bias table)

DEVI unsigned short f2b(float f) {
  union { float f; unsigned u; } v; v.f = f;
  unsigned r = v.u + 0x7fffu + ((v.u >> 16) & 1u);
  return (unsigned short)(r >> 16);
}

// ---------------- prep: weight transpose+bf16 (z=0..3) and bias MLP table (z=4) ----------------
__global__ __launch_bounds__(256) void k_prep(const float* Wa, const float* Wb,
                                              const float* Wc, const float* Wd,
                                              unsigned short* T0, unsigned short* T1,
                                              unsigned short* T2, unsigned short* T3,
                                              const float* mW1, const float* mb1,
                                              const float* mW2, const float* mb2,
                                              float* table) {
  if (blockIdx.z == 4) {
    if (blockIdx.y != 0) return;
    int idx = blockIdx.x * 256 + threadIdx.x;
    if (idx >= 63 * 63) return;
    int dy = idx / 63 - 31, dx = idx % 63 - 31;
    float r0 = copysignf(log1pf(fabsf((float)dy)), (float)dy);
    float r1 = copysignf(log1pf(fabsf((float)dx)), (float)dx);
    float acc[8];
#pragma unroll
    for (int h = 0; h < 8; ++h) acc[h] = mb2[h];
    for (int j = 0; j < 128; ++j) {
      float hv = fmaxf(r0 * mW1[j] + r1 * mW1[128 + j] + mb1[j], 0.f);
#pragma unroll
      for (int h = 0; h < 8; ++h) acc[h] += hv * mW2[j * 8 + h];
    }
#pragma unroll
    for (int h = 0; h < 8; ++h) table[h * 3969 + idx] = acc[h] - CSH;  // shift folded in
    return;
  }
  const float* W = blockIdx.z == 0 ? Wa : blockIdx.z == 1 ? Wb : blockIdx.z == 2 ? Wc : Wd;
  unsigned short* T = blockIdx.z == 0 ? T0 : blockIdx.z == 1 ? T1 : blockIdx.z == 2 ? T2 : T3;
  __shared__ float tile[32][33];
  int tx = threadIdx.x & 31, ty = threadIdx.x >> 5;
  int n0 = blockIdx.x * 32, k0 = blockIdx.y * 32;
#pragma unroll
  for (int r = 0; r < 4; ++r) tile[ty + r * 8][tx] = W[(size_t)(k0 + ty + r * 8) * D_ + n0 + tx];
  __syncthreads();
#pragma unroll
  for (int r = 0; r < 4; ++r) T[(size_t)(n0 + ty + r * 8) * D_ + k0 + tx] = f2b(tile[tx][ty + r * 8]);
}

// ---------------- merged QKV GEMM, 64x128 tiles, BK=64; V written pre-transposed ----------------
__global__ __launch_bounds__(256) void k_gemm_qkv(const float* Aq, const float* Ak, const float* Av,
                                                  const unsigned short* Tq, const unsigned short* Tk,
                                                  const unsigned short* Tv,
                                                  const float* bqv, const float* bkv, const float* bvv,
                                                  unsigned short* Oq, unsigned short* Ok,
                                                  unsigned short* OvT) {
  const float* A = blockIdx.z == 0 ? Aq : blockIdx.z == 1 ? Ak : Av;
  const unsigned short* BT = blockIdx.z == 0 ? Tq : blockIdx.z == 1 ? Tk : Tv;
  const float* bias = blockIdx.z == 0 ? bqv : blockIdx.z == 1 ? bkv : bvv;

  __shared__ unsigned short As[64][72];   // +8 pad: 144B row stride
  __shared__ unsigned short Bs[128][72];
  const int tid = threadIdx.x;
  const int lane = tid & 63, wave = tid >> 6;
  const int lr = lane & 15, lg = lane >> 4;
  const int wm = (wave >> 1) * 32, wn = (wave & 1) * 64;
  const int m0 = blockIdx.x * 64, n0 = blockIdx.y * 128;

  f32x4 acc[2][4];
#pragma unroll
  for (int i = 0; i < 2; ++i)
#pragma unroll
    for (int j = 0; j < 4; ++j) acc[i][j] = (f32x4){0.f, 0.f, 0.f, 0.f};

  for (int k0 = 0; k0 < 512; k0 += 64) {
#pragma unroll
    for (int i = 0; i < 4; ++i) {   // A: 64 rows x 16 float4 chunks = 1024 tasks
      int idx = tid + i * 256;
      int r = idx >> 4, c4 = (idx & 15) * 4;
      float4 fv = *(const float4*)(A + (size_t)(m0 + r) * 512 + k0 + c4);
      u16x4 wv;
      wv[0] = f2b(fv.x); wv[1] = f2b(fv.y); wv[2] = f2b(fv.z); wv[3] = f2b(fv.w);
      *(u16x4*)&As[r][c4] = wv;
    }
#pragma unroll
    for (int i = 0; i < 8; ++i) {   // B: 128 rows x 16 u16x4 chunks = 2048 tasks
      int idx = tid + i * 256;
      int r = idx >> 4, c4 = (idx & 15) * 4;
      *(u16x4*)&Bs[r][c4] = *(const u16x4*)(BT + (size_t)(n0 + r) * 512 + k0 + c4);
    }
    __syncthreads();
#pragma unroll
    for (int kk = 0; kk < 2; ++kk) {
      bf16x8 af[2], bg[4];
#pragma unroll
      for (int i = 0; i < 2; ++i) af[i] = *(const bf16x8*)&As[wm + i * 16 + lr][kk * 32 + lg * 8];
#pragma unroll
      for (int j = 0; j < 4; ++j) bg[j] = *(const bf16x8*)&Bs[wn + j * 16 + lr][kk * 32 + lg * 8];
#pragma unroll
      for (int i = 0; i < 2; ++i)
#pragma unroll
        for (int j = 0; j < 4; ++j)
          acc[i][j] = __builtin_amdgcn_mfma_f32_16x16x32_bf16(af[i], bg[j], acc[i][j], 0, 0, 0);
    }
    __syncthreads();
  }

#pragma unroll
  for (int i = 0; i < 2; ++i)
#pragma unroll
    for (int j = 0; j < 4; ++j) {
      int mbase = m0 + wm + i * 16 + lg * 4;
      int n = n0 + wn + j * 16 + lr;
      float bvl = bias[n];
      int h = n >> 6, hd = n & 63;
      int bseg = mbase >> 10, s0 = mbase & 1023;
      if (blockIdx.z == 2) {
        u16x4 pk;
#pragma unroll
        for (int r = 0; r < 4; ++r) pk[r] = f2b(acc[i][j][r] + bvl);
        *(u16x4*)(OvT + (((size_t)(bseg * H_ + h) * 64 + hd) * 1024 + s0)) = pk;
      } else {
        unsigned short* outp = blockIdx.z == 0 ? Oq : Ok;
#pragma unroll
        for (int r = 0; r < 4; ++r) {
          float v = acc[i][j][r] + bvl;
          outp[(((size_t)bseg * H_ + h) * S_ + s0 + r) * HD_ + hd] = f2b(v);
        }
      }
    }
}

// ---------------- output projection GEMM, 64x128 tiles, BK=64: bf16 A @ W^T + bias -> fp32 ----------------
__global__ __launch_bounds__(256) void k_gemm_out(const unsigned short* A, const unsigned short* BT,
                                                  const float* bias, float* outp) {
  __shared__ unsigned short As[64][72];
  __shared__ unsigned short Bs[128][72];
  const int tid = threadIdx.x;
  const int lane = tid & 63, wave = tid >> 6;
  const int lr = lane & 15, lg = lane >> 4;
  const int wm = (wave >> 1) * 32, wn = (wave & 1) * 64;
  const int m0 = blockIdx.x * 64, n0 = blockIdx.y * 128;

  f32x4 acc[2][4];
#pragma unroll
  for (int i = 0; i < 2; ++i)
#pragma unroll
    for (int j = 0; j < 4; ++j) acc[i][j] = (f32x4){0.f, 0.f, 0.f, 0.f};

  for (int k0 = 0; k0 < 512; k0 += 64) {
#pragma unroll
    for (int i = 0; i < 4; ++i) {
      int idx = tid + i * 256;
      int r = idx >> 4, c4 = (idx & 15) * 4;
      *(u16x4*)&As[r][c4] = *(const u16x4*)(A + (size_t)(m0 + r) * 512 + k0 + c4);
    }
#pragma unroll
    for (int i = 0; i < 8; ++i) {
      int idx = tid + i * 256;
      int r = idx >> 4, c4 = (idx & 15) * 4;
      *(u16x4*)&Bs[r][c4] = *(const u16x4*)(BT + (size_t)(n0 + r) * 512 + k0 + c4);
    }
    __syncthreads();
#pragma unroll
    for (int kk = 0; kk < 2; ++kk) {
      bf16x8 af[2], bg[4];
#pragma unroll
      for (int i = 0; i < 2; ++i) af[i] = *(const bf16x8*)&As[wm + i * 16 + lr][kk * 32 + lg * 8];
#pragma unroll
      for (int j = 0; j < 4; ++j) bg[j] = *(const bf16x8*)&Bs[wn + j * 16 + lr][kk * 32 + lg * 8];
#pragma unroll
      for (int i = 0; i < 2; ++i)
#pragma unroll
        for (int j = 0; j < 4; ++j)
          acc[i][j] = __builtin_amdgcn_mfma_f32_16x16x32_bf16(af[i], bg[j], acc[i][j], 0, 0, 0);
    }
    __syncthreads();
  }

#pragma unroll
  for (int i = 0; i < 2; ++i)
#pragma unroll
    for (int j = 0; j < 4; ++j) {
      int mbase = m0 + wm + i * 16 + lg * 4;
      int n = n0 + wn + j * 16 + lr;
      float bvl = bias[n];
#pragma unroll
      for (int r = 0; r < 4; ++r)
        outp[(size_t)(mbase + r) * 512 + n] = acc[i][j][r] + bvl;
    }
}

// ---------------- fused two-pass attention: 256 thr / 4 waves / 64 q-rows; dbuf, 1 barrier/tile ----------------
__global__ __launch_bounds__(256) void k_attn(const unsigned short* Qb, const unsigned short* Kb,
                                              const unsigned short* VT, const float* tbl,
                                              const int* mask, float* out_attn,
                                              unsigned short* Xp) {
  const int tid = threadIdx.x;
  const int lane = tid & 63, w = tid >> 6;
  const int lr = lane & 15, lg = lane >> 4;
  const int bh = blockIdx.y, b = bh >> 3, h = bh & 7;
  const int q0 = blockIdx.x * 64;

  __shared__ unsigned short Ks[2][64][64];   // K tiles, dbuf, XOR-swizzled 16B chunks
  __shared__ unsigned short Vt[2][64][64];   // V^T tiles, dbuf, same swizzle
  __shared__ unsigned short Pl[4][16][64];   // per-wave P tile
  __shared__ float biasT[3969];
  __shared__ float mbig[1024];
  __shared__ int tbad[16];

  const unsigned short* Qh = Qb + (size_t)bh * (S_ * HD_);
  const unsigned short* Kh = Kb + (size_t)bh * (S_ * HD_);
  const unsigned short* Vth = VT + (size_t)bh * (HD_ * S_);

  const int srow = tid >> 3, sc = tid & 7;         // 32 rows per pass; rows srow and srow+32
  const int swz = (sc ^ (srow & 7)) * 8;           // (srow+32)&7 == srow&7

  if (tid < 16) tbad[tid] = 0;
  __syncthreads();
  for (int i = tid; i < 3969; i += 256) biasT[i] = tbl[h * 3969 + i];
  {
    int4 mv = *(const int4*)(mask + b * S_ + tid * 4);
    int base = tid * 4;
    mbig[base] = mv.x ? 3.0e38f : -1.0e9f;
    mbig[base + 1] = mv.y ? 3.0e38f : -1.0e9f;
    mbig[base + 2] = mv.z ? 3.0e38f : -1.0e9f;
    mbig[base + 3] = mv.w ? 3.0e38f : -1.0e9f;
    if (!(mv.x && mv.y && mv.z && mv.w)) tbad[base >> 6] = 1;
  }
  // prologue: K tile 0
  *(bf16x8*)&Ks[0][srow][swz] = *(const bf16x8*)(Kh + (size_t)srow * 64 + sc * 8);
  *(bf16x8*)&Ks[0][srow + 32][swz] = *(const bf16x8*)(Kh + (size_t)(srow + 32) * 64 + sc * 8);

  const int qrow = q0 + w * 16 + lr;
  const bf16x8 bq0 = *(const bf16x8*)(Qh + (size_t)qrow * 64 + lg * 8);
  const bf16x8 bq1 = *(const bf16x8*)(Qh + (size_t)qrow * 64 + 32 + lg * 8);
  const int qterm = (qrow >> 5) * 63 + (qrow & 31) + 1984;

  float ls = 0.f;
  __syncthreads();

  // ---- PASS 1: row sums (fixed-shift softmax) ----
  for (int kt = 0; kt < 16; ++kt) {
    const int cur = kt & 1;
    bf16x8 nk0, nk1;
    if (kt < 15) {
      nk0 = *(const bf16x8*)(Kh + (size_t)((kt + 1) * 64 + srow) * 64 + sc * 8);
      nk1 = *(const bf16x8*)(Kh + (size_t)((kt + 1) * 64 + srow + 32) * 64 + sc * 8);
    }
    const int bidx = qterm - 126 * kt;
    const bool bad = tbad[kt] != 0;
#pragma unroll
    for (int fn = 0; fn < 4; ++fn) {
      const unsigned short* krow = &Ks[cur][fn * 16 + lr][0];
      bf16x8 a0 = *(const bf16x8*)(krow + (lg ^ (lr & 7)) * 8);
      bf16x8 a1 = *(const bf16x8*)(krow + ((4 + lg) ^ (lr & 7)) * 8);
      f32x4 s = (f32x4){0.f, 0.f, 0.f, 0.f};
      s = __builtin_amdgcn_mfma_f32_16x16x32_bf16(a0, bq0, s, 0, 0, 0);
      s = __builtin_amdgcn_mfma_f32_16x16x32_bf16(a1, bq1, s, 0, 0, 0);
      const int kob = fn * 16 + lg * 4;
      const int ib = bidx - kob - (fn >= 2 ? 31 : 0);
#pragma unroll
      for (int r = 0; r < 4; ++r) {
        float arg = fmaf(s[r], 0.125f, biasT[ib - r]);
        if (bad) arg = fminf(arg, mbig[kt * 64 + kob + r]);
        ls += __expf(arg);
      }
    }
    if (kt < 15) {
      *(bf16x8*)&Ks[cur ^ 1][srow][swz] = nk0;
      *(bf16x8*)&Ks[cur ^ 1][srow + 32][swz] = nk1;
    }
    __syncthreads();
  }
  ls += __shfl_xor(ls, 16, 64);
  ls += __shfl_xor(ls, 32, 64);
  const float inv = 1.f / ls;

  // ---- PASS 2: recompute, write attention (float4), accumulate PV ----
  f32x4 of[4];
#pragma unroll
  for (int i = 0; i < 4; ++i) of[i] = (f32x4){0.f, 0.f, 0.f, 0.f};
  float* oa = out_attn + (size_t)bh * (S_ * S_) + (size_t)qrow * S_;

  *(bf16x8*)&Ks[0][srow][swz] = *(const bf16x8*)(Kh + (size_t)srow * 64 + sc * 8);
  *(bf16x8*)&Ks[0][srow + 32][swz] = *(const bf16x8*)(Kh + (size_t)(srow + 32) * 64 + sc * 8);
  *(bf16x8*)&Vt[0][srow][swz] = *(const bf16x8*)(Vth + (size_t)srow * S_ + sc * 8);
  *(bf16x8*)&Vt[0][srow + 32][swz] = *(const bf16x8*)(Vth + (size_t)(srow + 32) * S_ + sc * 8);
  __syncthreads();

  for (int kt = 0; kt < 16; ++kt) {
    const int cur = kt & 1;
    bf16x8 nk0, nk1, nv0, nv1;
    if (kt < 15) {
      nk0 = *(const bf16x8*)(Kh + (size_t)((kt + 1) * 64 + srow) * 64 + sc * 8);
      nk1 = *(const bf16x8*)(Kh + (size_t)((kt + 1) * 64 + srow + 32) * 64 + sc * 8);
      nv0 = *(const bf16x8*)(Vth + (size_t)srow * S_ + (kt + 1) * 64 + sc * 8);
      nv1 = *(const bf16x8*)(Vth + (size_t)(srow + 32) * S_ + (kt + 1) * 64 + sc * 8);
    }
    const int bidx = qterm - 126 * kt;
    const bool bad = tbad[kt] != 0;
#pragma unroll
    for (int fn = 0; fn < 4; ++fn) {
      const unsigned short* krow = &Ks[cur][fn * 16 + lr][0];
      bf16x8 a0 = *(const bf16x8*)(krow + (lg ^ (lr & 7)) * 8);
      bf16x8 a1 = *(const bf16x8*)(krow + ((4 + lg) ^ (lr & 7)) * 8);
      f32x4 s = (f32x4){0.f, 0.f, 0.f, 0.f};
      s = __builtin_amdgcn_mfma_f32_16x16x32_bf16(a0, bq0, s, 0, 0, 0);
      s = __builtin_amdgcn_mfma_f32_16x16x32_bf16(a1, bq1, s, 0, 0, 0);
      const int kob = fn * 16 + lg * 4;
      const int ib = bidx - kob - (fn >= 2 ? 31 : 0);
      f32x4 pr;
      u16x4 pb;
#pragma unroll
      for (int r = 0; r < 4; ++r) {
        float arg = fmaf(s[r], 0.125f, biasT[ib - r]);
        if (bad) arg = fminf(arg, mbig[kt * 64 + kob + r]);
        float p = __expf(arg) * inv;
        pr[r] = p;
        pb[r] = f2b(p);
      }
      *(f32x4*)(oa + kt * 64 + kob) = pr;
      *(u16x4*)((char*)&Pl[w][lr][0] + ((fn * 2 + (lg >> 1)) ^ (lr & 7)) * 16 + (lg & 1) * 8) = pb;
    }
    // PV: O[q][d] += P[q][k] V[k][d]  (per-wave Pl; same-wave dependency)
#pragma unroll
    for (int c = 0; c < 2; ++c) {
      bf16x8 pa = *(const bf16x8*)((const char*)&Pl[w][lr][0] + ((c * 4 + lg) ^ (lr & 7)) * 16);
#pragma unroll
      for (int fn2 = 0; fn2 < 4; ++fn2) {
        const unsigned short* vrow = &Vt[cur][fn2 * 16 + lr][0];
        bf16x8 bv = *(const bf16x8*)((const char*)vrow + ((c * 4 + lg) ^ (lr & 7)) * 16);
        of[fn2] = __builtin_amdgcn_mfma_f32_16x16x32_bf16(pa, bv, of[fn2], 0, 0, 0);
      }
    }
    if (kt < 15) {
      *(bf16x8*)&Ks[cur ^ 1][srow][swz] = nk0;
      *(bf16x8*)&Ks[cur ^ 1][srow + 32][swz] = nk1;
      *(bf16x8*)&Vt[cur ^ 1][srow][swz] = nv0;
      *(bf16x8*)&Vt[cur ^ 1][srow + 32][swz] = nv1;
    }
    __syncthreads();
  }

  // epilogue: x pre-projection, bf16 [B,S,D]
#pragma unroll
  for (int fn2 = 0; fn2 < 4; ++fn2)
#pragma unroll
    for (int r = 0; r < 4; ++r) {
      int q = q0 + w * 16 + lg * 4 + r;
      Xp[((size_t)b * S_ + q) * D_ + h * 64 + fn2 * 16 + lr] = f2b(of[fn2][r]);
    }
}

// ---------------- host launch ----------------
extern "C" void kernel_launch(void* const* d_in, const int* in_sizes, int n_in,
                              void* d_out, int out_size, void* d_ws, size_t ws_size,
                              hipStream_t stream) {
  const float* query = (const float*)d_in[0];
  const float* key   = (const float*)d_in[1];
  const float* value = (const float*)d_in[2];
  const int*   maskp = (const int*)d_in[3];
  const float* Wq = (const float*)d_in[4];
  const float* bq = (const float*)d_in[5];
  const float* Wk = (const float*)d_in[6];
  const float* bk = (const float*)d_in[7];
  const float* Wv = (const float*)d_in[8];
  const float* bv = (const float*)d_in[9];
  const float* Wo = (const float*)d_in[10];
  const float* bo = (const float*)d_in[11];
  const float* W1 = (const float*)d_in[12];
  const float* b1 = (const float*)d_in[13];
  const float* W2 = (const float*)d_in[14];
  const float* b2 = (const float*)d_in[15];

  char* ws = (char*)d_ws;
  const size_t MB4 = (size_t)4 * 1024 * 1024;
  unsigned short* Qb  = (unsigned short*)(ws);
  unsigned short* Kb  = (unsigned short*)(ws + MB4);
  unsigned short* VT  = (unsigned short*)(ws + 2 * MB4);
  unsigned short* Xp  = (unsigned short*)(ws + 3 * MB4);
  unsigned short* WqT = (unsigned short*)(ws + 4 * MB4);
  unsigned short* WkT = (unsigned short*)(ws + 4 * MB4 + 524288);
  unsigned short* WvT = (unsigned short*)(ws + 4 * MB4 + 2 * 524288);
  unsigned short* WoT = (unsigned short*)(ws + 4 * MB4 + 3 * 524288);
  float* table        = (float*)(ws + 4 * MB4 + 4 * 524288);

  float* out_x = (float*)d_out;
  float* out_attn = out_x + (size_t)B_ * S_ * D_;

  k_prep<<<dim3(16, 16, 5), 256, 0, stream>>>(Wq, Wk, Wv, Wo, WqT, WkT, WvT, WoT,
                                              W1, b1, W2, b2, table);
  k_gemm_qkv<<<dim3(64, 4, 3), 256, 0, stream>>>(query, key, value, WqT, WkT, WvT,
                                                 bq, bk, bv, Qb, Kb, VT);
  k_attn<<<dim3(16, 32), 256, 0, stream>>>(Qb, Kb, VT, table, maskp, out_attn, Xp);
  k_gemm_out<<<dim3(64, 4), 256, 0, stream>>>(Xp, WoT, bo, out_x);
}